// Round 5
// baseline (923.894 us; speedup 1.0000x reference)
//
#include <hip/hip_runtime.h>
#include <stdint.h>

#define D_DIM 1024
#define M_TOT 16384   // 8 * 2048
#define N_LAYERS 3
#define NT 16         // K tiles (K=1024 / BK=64)

typedef unsigned short u16;
typedef __attribute__((ext_vector_type(8))) short bf16x8;
typedef __attribute__((ext_vector_type(4))) float f32x4;
typedef __attribute__((ext_vector_type(4))) unsigned short u16x4;

typedef __attribute__((address_space(1))) void gvoid_t;
typedef __attribute__((address_space(3))) void lvoid_t;

__device__ __forceinline__ float b2f(u16 u) {
  union { unsigned int i; float f; } x; x.i = ((unsigned int)u) << 16; return x.f;
}
__device__ __forceinline__ u16 f2b(float f) {  // RNE f32 -> bf16
  union { float f; unsigned int i; } x; x.f = f;
  unsigned int r = x.i + 0x7fffu + ((x.i >> 16) & 1u);
  return (u16)(r >> 16);
}

__device__ __forceinline__ void gload_lds16(const void* g, void* l) {
  __builtin_amdgcn_global_load_lds((gvoid_t*)(uintptr_t)g,
                                   (lvoid_t*)(unsigned int)(uintptr_t)l, 16, 0, 0);
}

// Opaque LDS read; ordering via explicit counted lgkmcnt + sched_barrier (rule #18).
__device__ __forceinline__ bf16x8 dsr128(unsigned addr) {
  bf16x8 r;
  asm volatile("ds_read_b128 %0, %1" : "=v"(r) : "v"(addr));
  return r;
}

// ---------------------------------------------------------------------------
// 256x256 GEMM engine, ONE barrier per K-tile, software-pipelined ds_read.
// Per tile: stage tt+1 -> buf^1 (8 gload_lds; no WAR: buf^1 untouched this
// tile; all reads of buf^1-as-previous-buffer completed before the barrier we
// just passed). Issue all 24 ds_reads of buf cur (B 8, A 16; each dest reg
// written once -> no in-flight DS WAR). Counted lgkm waits (DS in-order):
// 24 issued; first 12 (B+A0) done at lgkmcnt(12); +4 per quadrant after.
// vmcnt(0) at tile end drains the 8 stage loads (issued ~2000 cyc earlier).
// EPI 0: outB = bf16(sigmoid(acc+bias) * xb * decay)
// EPI 1: outB = bf16(acc + bias + xb)            (pre-LN)
// EPI 2: outB = bf16(p*(acc+bias))               (MoE e0)
// EPI 3: outB = bf16(outB + p*(acc+bias))        (MoE e1,e2; bf16 RMW)
// EPI 4: outF = outB + p*(acc+bias)              (MoE e3; final f32)
// ---------------------------------------------------------------------------
template <int EPI>
__global__ __launch_bounds__(512, 2) void gemm8p(
    const u16* __restrict__ A, const u16* __restrict__ Bm,
    const float* __restrict__ bias, const float* __restrict__ decay,
    const u16* __restrict__ xfB, const float* __restrict__ probs, int eIdx,
    u16* __restrict__ outB, float* __restrict__ outF)
{
  __shared__ __align__(128) u16 lds[65536];   // 128 KB: 2 x {B 32KB, A 32KB}
  int t = threadIdx.x;
  int wid = t >> 6, l = t & 63;
  int wm = wid >> 2, wn = wid & 3;            // 2 x 4 waves; wave tile 128 x 64
  int lm = l & 15, g = l >> 4;

  int orig = blockIdx.x;                      // 256 wgs, 8 XCDs -> bijective
  int wg = ((orig & 7) << 5) | (orig >> 3);
  int bm0 = (wg >> 2) << 8, bn0 = (wg & 3) << 8;

  // staging source (pre-swizzled global col; LDS dest linear)
  int rowL = t >> 3;
  int colE = ((t & 7) ^ (rowL & 7)) << 3;
  const u16* pA = A + (size_t)(bm0 + ((rowL >> 5) << 7) + (rowL & 31)) * D_DIM + colE;
  const u16* pB = Bm + (size_t)(bn0 + rowL) * D_DIM + colE;
  u16* ldsW = lds + wid * 512;                // wave-uniform dst base

#define STAGE_B(tile, c) gload_lds16(pB + (size_t)(tile) * 64 + (size_t)(c) * 65536, \
                                     ldsW + ((tile) & 1) * 32768 + (c) * 4096)
#define STAGE_A(tile, q) gload_lds16(pA + (size_t)(tile) * 64 + (size_t)(q) * 32768, \
                                     ldsW + ((tile) & 1) * 32768 + 16384 + (q) * 4096)

  // read-side swizzled byte addresses
  unsigned lb = (unsigned)(uintptr_t)(const char*)lds;
  unsigned xc0 = (unsigned)((g * 16) ^ ((lm & 7) << 4));
  unsigned Bb0 = lb + wn * 8192 + lm * 128 + xc0;
  unsigned Bb1 = Bb0 ^ 64u;
  unsigned Ab0 = lb + 32768 + (wm * 32 + lm) * 128 + xc0;
  unsigned Ab1 = Ab0 ^ 64u;

  f32x4 acc[8][4];
#pragma unroll
  for (int mi = 0; mi < 8; mi++)
#pragma unroll
    for (int ni = 0; ni < 4; ni++) acc[mi][ni] = 0.0f;

  // prologue: stage tile0, drain, sync
#pragma unroll
  for (int c = 0; c < 4; c++) STAGE_B(0, c);
#pragma unroll
  for (int q = 0; q < 4; q++) STAGE_A(0, q);
  asm volatile("s_waitcnt vmcnt(0)" ::: "memory");
  __builtin_amdgcn_s_barrier();

#pragma unroll 2
  for (int tt = 0; tt < NT; ++tt) {
    const unsigned cb = (unsigned)(tt & 1) * 65536u;
    // stage next tile into the other buffer (issue early; hides under tile)
    if (tt + 1 < NT) {
#pragma unroll
      for (int c = 0; c < 4; c++) STAGE_B(tt + 1, c);
#pragma unroll
      for (int q = 0; q < 4; q++) STAGE_A(tt + 1, q);
    }
    // issue ALL ds_reads for this tile: B (8) then A q0..q3 (16)
    bf16x8 bfr[4][2];
#pragma unroll
    for (int ni = 0; ni < 4; ni++) {
      bfr[ni][0] = dsr128(Bb0 + cb + ni * 2048);
      bfr[ni][1] = dsr128(Bb1 + cb + ni * 2048);
    }
    bf16x8 av[4][2][2];
#pragma unroll
    for (int q = 0; q < 4; q++)
#pragma unroll
      for (int s = 0; s < 2; s++) {
        av[q][s][0] = dsr128(Ab0 + cb + q * 8192 + s * 2048);
        av[q][s][1] = dsr128(Ab1 + cb + q * 8192 + s * 2048);
      }
    // pipelined MFMA clusters with counted lgkm waits (DS in-order)
#pragma unroll
    for (int q = 0; q < 4; q++) {
      if (q == 0)      asm volatile("s_waitcnt lgkmcnt(12)");
      else if (q == 1) asm volatile("s_waitcnt lgkmcnt(8)");
      else if (q == 2) asm volatile("s_waitcnt lgkmcnt(4)");
      else             asm volatile("s_waitcnt lgkmcnt(0)");
      __builtin_amdgcn_sched_barrier(0);
      __builtin_amdgcn_s_setprio(1);
#pragma unroll
      for (int ks = 0; ks < 2; ks++)
#pragma unroll
        for (int s = 0; s < 2; s++)
#pragma unroll
          for (int ni = 0; ni < 4; ni++)
            acc[2 * q + s][ni] = __builtin_amdgcn_mfma_f32_16x16x32_bf16(
                av[q][s][ks], bfr[ni][ks], acc[2 * q + s][ni], 0, 0, 0);
      __builtin_amdgcn_s_setprio(0);
      __builtin_amdgcn_sched_barrier(0);
    }
    asm volatile("s_waitcnt vmcnt(0)" ::: "memory");   // next tile landed
    __builtin_amdgcn_s_barrier();
  }
#undef STAGE_A
#undef STAGE_B

  // ---- epilogue ----  m = bm0+wm*128+mi*16+g*4+j, n = bn0+wn*64+ni*16+lm
  int nidx[4]; float bia[4], dec[4];
#pragma unroll
  for (int ni = 0; ni < 4; ni++) {
    nidx[ni] = bn0 + wn * 64 + ni * 16 + lm;
    bia[ni] = bias[nidx[ni]];
    dec[ni] = (EPI == 0) ? decay[nidx[ni]] : 0.0f;
  }
#pragma unroll
  for (int mi = 0; mi < 8; mi++)
#pragma unroll
    for (int j = 0; j < 4; j++) {
      size_t m = (size_t)bm0 + wm * 128 + mi * 16 + g * 4 + j;
      if (EPI == 0) {
        const u16* xr = xfB + m * D_DIM;
        u16* orow = outB + m * D_DIM;
#pragma unroll
        for (int ni = 0; ni < 4; ni++) {
          float v = acc[mi][ni][j] + bia[ni];
          float gt = 1.0f / (1.0f + __expf(-v));
          orow[nidx[ni]] = f2b(gt * b2f(xr[nidx[ni]]) * dec[ni]);
        }
      } else if (EPI == 1) {
        const u16* xr = xfB + m * D_DIM;
        u16* orow = outB + m * D_DIM;
#pragma unroll
        for (int ni = 0; ni < 4; ni++)
          orow[nidx[ni]] = f2b(acc[mi][ni][j] + bia[ni] + b2f(xr[nidx[ni]]));
      } else if (EPI == 2) {
        float p = probs[m * 4 + eIdx];
        u16* orow = outB + m * D_DIM;
#pragma unroll
        for (int ni = 0; ni < 4; ni++)
          orow[nidx[ni]] = f2b(p * (acc[mi][ni][j] + bia[ni]));
      } else if (EPI == 3) {
        float p = probs[m * 4 + eIdx];
        u16* orow = outB + m * D_DIM;
#pragma unroll
        for (int ni = 0; ni < 4; ni++)
          orow[nidx[ni]] = f2b(b2f(orow[nidx[ni]]) + p * (acc[mi][ni][j] + bia[ni]));
      } else {
        float p = probs[m * 4 + eIdx];
        const u16* srow = outB + m * D_DIM;
        float* orow = outF + m * D_DIM;
#pragma unroll
        for (int ni = 0; ni < 4; ni++)
          orow[nidx[ni]] = b2f(srow[nidx[ni]]) + p * (acc[mi][ni][j] + bia[ni]);
      }
    }
}

// Row LayerNorm over D=1024 on bf16 input; writes bf16 (next A) and optionally f32.
template <int WF32>
__global__ __launch_bounds__(256) void ln_kernel(const u16* __restrict__ src,
                                                 const float* __restrict__ gamma,
                                                 const float* __restrict__ beta,
                                                 float* __restrict__ dstF, u16* __restrict__ dstB) {
  size_t row = blockIdx.x;
  int t = threadIdx.x, w = t >> 6, l = t & 63;
  u16x4 vb = ((const u16x4*)(src + row * D_DIM))[t];
  float v[4];
#pragma unroll
  for (int i = 0; i < 4; i++) v[i] = b2f(vb[i]);
  float s = v[0] + v[1] + v[2] + v[3];
  float q = v[0]*v[0] + v[1]*v[1] + v[2]*v[2] + v[3]*v[3];
#pragma unroll
  for (int off = 32; off; off >>= 1) { s += __shfl_xor(s, off); q += __shfl_xor(q, off); }
  __shared__ float red[8];
  if (l == 0) { red[w] = s; red[4 + w] = q; }
  __syncthreads();
  s = red[0] + red[1] + red[2] + red[3];
  q = red[4] + red[5] + red[6] + red[7];
  float mu = s * (1.0f / 1024.0f);
  float var = q * (1.0f / 1024.0f) - mu * mu;
  float inv = rsqrtf(var + 1e-5f);
  f32x4 gm = ((const f32x4*)gamma)[t], b = ((const f32x4*)beta)[t];
  f32x4 y; u16x4 yb;
#pragma unroll
  for (int i = 0; i < 4; i++) { y[i] = (v[i] - mu) * inv * gm[i] + b[i]; yb[i] = f2b(y[i]); }
  ((u16x4*)(dstB + row * D_DIM))[t] = yb;
  if (WF32) ((f32x4*)(dstF + row * D_DIM))[t] = y;
}

// f32 -> bf16 elementwise
__global__ void conv_kernel(const float* __restrict__ src, u16* __restrict__ dst, int n4) {
  int i = blockIdx.x * 256 + threadIdx.x;
  if (i >= n4) return;
  f32x4 v = ((const f32x4*)src)[i];
  u16x4 o;
#pragma unroll
  for (int j = 0; j < 4; j++) o[j] = f2b(v[j]);
  ((u16x4*)dst)[i] = o;
}

// Gate: logits + softmax -> probs[m,0..3]. One wave per row.
__global__ __launch_bounds__(256) void gate_kernel(const u16* __restrict__ zb,
                                                   const float* __restrict__ gW,
                                                   const float* __restrict__ gb,
                                                   float* __restrict__ probs) {
  __shared__ float sW[4096];
  int t = threadIdx.x;
#pragma unroll
  for (int c = 0; c < 4; c++) ((f32x4*)sW)[c * 256 + t] = ((const f32x4*)gW)[c * 256 + t];
  __syncthreads();
  int w = t >> 6, l = t & 63;
  size_t m = (size_t)blockIdx.x * 4 + w;
  const u16* zr = zb + m * D_DIM;
  float d0 = 0, d1 = 0, d2 = 0, d3 = 0;
#pragma unroll
  for (int c = 0; c < 4; c++) {
    int k = l * 4 + c * 256;
    u16x4 zv = *(const u16x4*)(zr + k);
    f32x4 w0 = *(const f32x4*)&sW[k];
    f32x4 w1 = *(const f32x4*)&sW[1024 + k];
    f32x4 w2 = *(const f32x4*)&sW[2048 + k];
    f32x4 w3 = *(const f32x4*)&sW[3072 + k];
#pragma unroll
    for (int i = 0; i < 4; i++) {
      float zf = b2f(zv[i]);
      d0 += zf * w0[i]; d1 += zf * w1[i]; d2 += zf * w2[i]; d3 += zf * w3[i];
    }
  }
#pragma unroll
  for (int off = 32; off; off >>= 1) {
    d0 += __shfl_xor(d0, off); d1 += __shfl_xor(d1, off);
    d2 += __shfl_xor(d2, off); d3 += __shfl_xor(d3, off);
  }
  if (l == 0) {
    float l0 = d0 + gb[0], l1 = d1 + gb[1], l2 = d2 + gb[2], l3 = d3 + gb[3];
    float mx = fmaxf(fmaxf(l0, l1), fmaxf(l2, l3));
    float e0 = __expf(l0 - mx), e1 = __expf(l1 - mx), e2 = __expf(l2 - mx), e3 = __expf(l3 - mx);
    float inv = 1.0f / (e0 + e1 + e2 + e3);
    f32x4 r; r[0] = e0 * inv; r[1] = e1 * inv; r[2] = e2 * inv; r[3] = e3 * inv;
    ((f32x4*)(probs + m * 4))[0] = r;
  }
}

extern "C" void kernel_launch(void* const* d_in, const int* in_sizes, int n_in,
                              void* d_out, int out_size, void* d_ws, size_t ws_size,
                              hipStream_t stream) {
  (void)in_sizes; (void)n_in; (void)out_size; (void)ws_size;
  const float* x_ctx    = (const float*)d_in[0];
  const float* x_tgt    = (const float*)d_in[1];
  const float* enc_Win  = (const float*)d_in[2];
  const float* enc_bin  = (const float*)d_in[3];
  const float* enc_dec  = (const float*)d_in[4];
  const float* enc_Wout = (const float*)d_in[5];
  const float* enc_bout = (const float*)d_in[6];
  const float* enc_gam  = (const float*)d_in[7];
  const float* enc_bet  = (const float*)d_in[8];
  const float* tgt_Win  = (const float*)d_in[9];
  const float* tgt_bin  = (const float*)d_in[10];
  const float* tgt_dec  = (const float*)d_in[11];
  const float* tgt_Wout = (const float*)d_in[12];
  const float* tgt_bout = (const float*)d_in[13];
  const float* tgt_gam  = (const float*)d_in[14];
  const float* tgt_bet  = (const float*)d_in[15];
  const float* gate_W   = (const float*)d_in[16];
  const float* gate_b   = (const float*)d_in[17];
  const float* exp_W    = (const float*)d_in[18];
  const float* exp_b    = (const float*)d_in[19];

  // d_out: pred_z[16M] | gate_probs[64K] | z_target[16M]
  float* out_pred  = (float*)d_out;
  float* out_probs = out_pred + (size_t)M_TOT * D_DIM;
  float* out_ztgt  = out_probs + (size_t)M_TOT * 4;

  // ws: bf16 weights (32MB) | xb(32MB) | sb(32MB) | ob(32MB)
  char* ws = (char*)d_ws;
  u16* wbEncIn  = (u16*)ws;
  u16* wbEncOut = wbEncIn  + (size_t)3 * 1048576;
  u16* wbTgtIn  = wbEncOut + (size_t)3 * 1048576;
  u16* wbTgtOut = wbTgtIn  + (size_t)3 * 1048576;
  u16* wbExp    = wbTgtOut + (size_t)3 * 1048576;
  u16* xb       = wbExp    + (size_t)4 * 1048576;
  u16* sb       = xb + (size_t)M_TOT * D_DIM;
  u16* ob       = sb + (size_t)M_TOT * D_DIM;

  auto conv = [&](const float* s, u16* d, size_t n) {
    int n4 = (int)(n / 4);
    conv_kernel<<<(n4 + 255) / 256, 256, 0, stream>>>(s, d, n4);
  };
  conv(enc_Win,  wbEncIn,  (size_t)3 * 1048576);
  conv(enc_Wout, wbEncOut, (size_t)3 * 1048576);
  conv(tgt_Win,  wbTgtIn,  (size_t)3 * 1048576);
  conv(tgt_Wout, wbTgtOut, (size_t)3 * 1048576);
  conv(exp_W,    wbExp,    (size_t)4 * 1048576);

  // ---- target stack ----
  conv(x_tgt, xb, (size_t)M_TOT * D_DIM);
  for (int i = 0; i < N_LAYERS; i++) {
    gemm8p<0><<<256, 512, 0, stream>>>(xb, wbTgtIn + (size_t)i * 1048576,
                                       tgt_bin + i * 1024, tgt_dec + i * 1024, xb,
                                       nullptr, 0, sb, nullptr);
    gemm8p<1><<<256, 512, 0, stream>>>(sb, wbTgtOut + (size_t)i * 1048576,
                                       tgt_bout + i * 1024, nullptr, xb,
                                       nullptr, 0, ob, nullptr);
    if (i == N_LAYERS - 1)
      ln_kernel<1><<<M_TOT, 256, 0, stream>>>(ob, tgt_gam + i * 1024, tgt_bet + i * 1024, out_ztgt, xb);
    else
      ln_kernel<0><<<M_TOT, 256, 0, stream>>>(ob, tgt_gam + i * 1024, tgt_bet + i * 1024, nullptr, xb);
  }

  // ---- context stack ----
  conv(x_ctx, xb, (size_t)M_TOT * D_DIM);
  for (int i = 0; i < N_LAYERS; i++) {
    gemm8p<0><<<256, 512, 0, stream>>>(xb, wbEncIn + (size_t)i * 1048576,
                                       enc_bin + i * 1024, enc_dec + i * 1024, xb,
                                       nullptr, 0, sb, nullptr);
    gemm8p<1><<<256, 512, 0, stream>>>(sb, wbEncOut + (size_t)i * 1048576,
                                       enc_bout + i * 1024, nullptr, xb,
                                       nullptr, 0, ob, nullptr);
    ln_kernel<0><<<M_TOT, 256, 0, stream>>>(ob, enc_gam + i * 1024, enc_bet + i * 1024, nullptr, xb);
  }

  // ---- MoE head: gate probs, then 4 passes; bf16 running sum in sb ----
  gate_kernel<<<M_TOT / 4, 256, 0, stream>>>(xb, gate_W, gate_b, out_probs);
  gemm8p<2><<<256, 512, 0, stream>>>(xb, wbExp,               exp_b,        nullptr, nullptr,
                                     out_probs, 0, sb, nullptr);
  gemm8p<3><<<256, 512, 0, stream>>>(xb, wbExp + 1048576,     exp_b + 1024, nullptr, nullptr,
                                     out_probs, 1, sb, nullptr);
  gemm8p<3><<<256, 512, 0, stream>>>(xb, wbExp + 2 * 1048576, exp_b + 2048, nullptr, nullptr,
                                     out_probs, 2, sb, nullptr);
  gemm8p<4><<<256, 512, 0, stream>>>(xb, wbExp + 3 * 1048576, exp_b + 3072, nullptr, nullptr,
                                     out_probs, 3, sb, out_pred);
}

// Round 6
// 808.900 us; speedup vs baseline: 1.1422x; 1.1422x over previous
//
#include <hip/hip_runtime.h>
#include <stdint.h>

#define D_DIM 1024
#define M_TOT 16384   // 8 * 2048
#define N_LAYERS 3
#define NT 16         // K tiles (K=1024 / BK=64)

typedef unsigned short u16;
typedef __attribute__((ext_vector_type(8))) short bf16x8;
typedef __attribute__((ext_vector_type(4))) float f32x4;
typedef __attribute__((ext_vector_type(4))) unsigned short u16x4;

typedef __attribute__((address_space(1))) void gvoid_t;
typedef __attribute__((address_space(3))) void lvoid_t;

__device__ __forceinline__ float b2f(u16 u) {
  union { unsigned int i; float f; } x; x.i = ((unsigned int)u) << 16; return x.f;
}
__device__ __forceinline__ u16 f2b(float f) {  // RNE f32 -> bf16
  union { float f; unsigned int i; } x; x.f = f;
  unsigned int r = x.i + 0x7fffu + ((x.i >> 16) & 1u);
  return (u16)(r >> 16);
}

__device__ __forceinline__ void gload_lds16(const void* g, void* l) {
  __builtin_amdgcn_global_load_lds((gvoid_t*)(uintptr_t)g,
                                   (lvoid_t*)(unsigned int)(uintptr_t)l, 16, 0, 0);
}

// Opaque LDS read; ordering via explicit counted lgkmcnt + sched_barrier (rule #18).
__device__ __forceinline__ bf16x8 dsr128(unsigned addr) {
  bf16x8 r;
  asm volatile("ds_read_b128 %0, %1" : "=v"(r) : "v"(addr));
  return r;
}

// ---------------------------------------------------------------------------
// 256x256 GEMM engine, ONE barrier per K-tile, depth-1 quadrant pipelining.
// Per tile per wave (program order; DS returns in-order):
//   stage tile tt+1 -> buf^1 (8 gload_lds; vmcnt only)        [hidden]
//   ds_read B(8), A0(4)->aE, A1(4)->aO                         [16 issued]
//   lgkm(4) [B+A0 done] -> MFMA q0(aE) -> read A2->aE
//   lgkm(4) [A1 done]   -> MFMA q1(aO) -> read A3->aO
//   lgkm(4) [A2 done]   -> MFMA q2(aE)
//   lgkm(0) [A3 done]   -> MFMA q3(aO)
//   vmcnt(0) [stage issued ~2500 cyc ago: near-free] -> s_barrier
// WAR on buf^1: its readers (tile tt-1) finished before the tile-(tt-1)
// barrier, which precedes this stage. RAW on buf cur: vmcnt(0)+barrier at
// end of tile tt-1. Peak live regs ~192 (acc128 + B32 + 2x A16) -> no spill.
// EPI 0: outB = bf16(sigmoid(acc+bias) * xb * decay)
// EPI 1: outB = bf16(acc + bias + xb)            (pre-LN)
// EPI 2: outB = bf16(p*(acc+bias))               (MoE e0)
// EPI 3: outB = bf16(outB + p*(acc+bias))        (MoE e1,e2; bf16 RMW)
// EPI 4: outF = outB + p*(acc+bias)              (MoE e3; final f32)
// ---------------------------------------------------------------------------
template <int EPI>
__global__ __launch_bounds__(512, 2) void gemm8p(
    const u16* __restrict__ A, const u16* __restrict__ Bm,
    const float* __restrict__ bias, const float* __restrict__ decay,
    const u16* __restrict__ xfB, const float* __restrict__ probs, int eIdx,
    u16* __restrict__ outB, float* __restrict__ outF)
{
  __shared__ __align__(128) u16 lds[65536];   // 128 KB: 2 x {B 32KB, A 32KB}
  int t = threadIdx.x;
  int wid = t >> 6, l = t & 63;
  int wm = wid >> 2, wn = wid & 3;            // 2 x 4 waves; wave tile 128 x 64
  int lm = l & 15, g = l >> 4;

  int orig = blockIdx.x;                      // 256 wgs, 8 XCDs -> bijective
  int wg = ((orig & 7) << 5) | (orig >> 3);
  int bm0 = (wg >> 2) << 8, bn0 = (wg & 3) << 8;

  // staging source (pre-swizzled global col; LDS dest linear)
  int rowL = t >> 3;
  int colE = ((t & 7) ^ (rowL & 7)) << 3;
  const u16* pA = A + (size_t)(bm0 + ((rowL >> 5) << 7) + (rowL & 31)) * D_DIM + colE;
  const u16* pB = Bm + (size_t)(bn0 + rowL) * D_DIM + colE;
  u16* ldsW = lds + wid * 512;                // wave-uniform dst base

#define STAGE_B(tile, c) gload_lds16(pB + (size_t)(tile) * 64 + (size_t)(c) * 65536, \
                                     ldsW + ((tile) & 1) * 32768 + (c) * 4096)
#define STAGE_A(tile, q) gload_lds16(pA + (size_t)(tile) * 64 + (size_t)(q) * 32768, \
                                     ldsW + ((tile) & 1) * 32768 + 16384 + (q) * 4096)

  // read-side swizzled byte addresses
  unsigned lb = (unsigned)(uintptr_t)(const char*)lds;
  unsigned xc0 = (unsigned)((g * 16) ^ ((lm & 7) << 4));
  unsigned Bb0 = lb + wn * 8192 + lm * 128 + xc0;
  unsigned Bb1 = Bb0 ^ 64u;
  unsigned Ab0 = lb + 32768 + (wm * 32 + lm) * 128 + xc0;
  unsigned Ab1 = Ab0 ^ 64u;

  f32x4 acc[8][4];
#pragma unroll
  for (int mi = 0; mi < 8; mi++)
#pragma unroll
    for (int ni = 0; ni < 4; ni++) acc[mi][ni] = 0.0f;

#define READ_A(dst, q)                                                        \
  _Pragma("unroll")                                                           \
  for (int s = 0; s < 2; s++) {                                               \
    dst[s][0] = dsr128(Ab0 + cb + (q) * 8192 + s * 2048);                     \
    dst[s][1] = dsr128(Ab1 + cb + (q) * 8192 + s * 2048);                     \
  }

#define CLUSTER(q, ab)                                                        \
  __builtin_amdgcn_sched_barrier(0);                                          \
  __builtin_amdgcn_s_setprio(1);                                              \
  _Pragma("unroll")                                                           \
  for (int ks = 0; ks < 2; ks++)                                              \
    _Pragma("unroll")                                                         \
    for (int s = 0; s < 2; s++)                                               \
      _Pragma("unroll")                                                       \
      for (int ni = 0; ni < 4; ni++)                                          \
        acc[2 * (q) + s][ni] = __builtin_amdgcn_mfma_f32_16x16x32_bf16(       \
            ab[s][ks], bfr[ni][ks], acc[2 * (q) + s][ni], 0, 0, 0);           \
  __builtin_amdgcn_s_setprio(0);                                              \
  __builtin_amdgcn_sched_barrier(0);

  // prologue: stage tile0, drain, sync
#pragma unroll
  for (int c = 0; c < 4; c++) STAGE_B(0, c);
#pragma unroll
  for (int q = 0; q < 4; q++) STAGE_A(0, q);
  asm volatile("s_waitcnt vmcnt(0)" ::: "memory");
  __builtin_amdgcn_s_barrier();

#pragma unroll 2
  for (int tt = 0; tt < NT; ++tt) {
    const unsigned cb = (unsigned)(tt & 1) * 65536u;
    // stage next tile into the other buffer (issue early; hides under tile)
    if (tt + 1 < NT) {
#pragma unroll
      for (int c = 0; c < 4; c++) STAGE_B(tt + 1, c);
#pragma unroll
      for (int q = 0; q < 4; q++) STAGE_A(tt + 1, q);
    }
    // issue B (8) + A0 (4) + A1 (4)
    bf16x8 bfr[4][2];
#pragma unroll
    for (int ni = 0; ni < 4; ni++) {
      bfr[ni][0] = dsr128(Bb0 + cb + ni * 2048);
      bfr[ni][1] = dsr128(Bb1 + cb + ni * 2048);
    }
    bf16x8 aE[2][2], aO[2][2];
    READ_A(aE, 0);
    READ_A(aO, 1);

    asm volatile("s_waitcnt lgkmcnt(4)");   // B + A0 done (A1 may be pending)
    CLUSTER(0, aE);
    READ_A(aE, 2);
    asm volatile("s_waitcnt lgkmcnt(4)");   // A1 done (A2 may be pending)
    CLUSTER(1, aO);
    READ_A(aO, 3);
    asm volatile("s_waitcnt lgkmcnt(4)");   // A2 done (A3 may be pending)
    CLUSTER(2, aE);
    asm volatile("s_waitcnt lgkmcnt(0)");   // A3 done
    CLUSTER(3, aO);

    asm volatile("s_waitcnt vmcnt(0)" ::: "memory");   // next tile landed (issued ~tile ago)
    __builtin_amdgcn_s_barrier();
  }
#undef STAGE_A
#undef STAGE_B
#undef READ_A
#undef CLUSTER

  // ---- epilogue ----  m = bm0+wm*128+mi*16+g*4+j, n = bn0+wn*64+ni*16+lm
  int nidx[4]; float bia[4], dec[4];
#pragma unroll
  for (int ni = 0; ni < 4; ni++) {
    nidx[ni] = bn0 + wn * 64 + ni * 16 + lm;
    bia[ni] = bias[nidx[ni]];
    dec[ni] = (EPI == 0) ? decay[nidx[ni]] : 0.0f;
  }
#pragma unroll
  for (int mi = 0; mi < 8; mi++)
#pragma unroll
    for (int j = 0; j < 4; j++) {
      size_t m = (size_t)bm0 + wm * 128 + mi * 16 + g * 4 + j;
      if (EPI == 0) {
        const u16* xr = xfB + m * D_DIM;
        u16* orow = outB + m * D_DIM;
#pragma unroll
        for (int ni = 0; ni < 4; ni++) {
          float v = acc[mi][ni][j] + bia[ni];
          float gt = 1.0f / (1.0f + __expf(-v));
          orow[nidx[ni]] = f2b(gt * b2f(xr[nidx[ni]]) * dec[ni]);
        }
      } else if (EPI == 1) {
        const u16* xr = xfB + m * D_DIM;
        u16* orow = outB + m * D_DIM;
#pragma unroll
        for (int ni = 0; ni < 4; ni++)
          orow[nidx[ni]] = f2b(acc[mi][ni][j] + bia[ni] + b2f(xr[nidx[ni]]));
      } else if (EPI == 2) {
        float p = probs[m * 4 + eIdx];
        u16* orow = outB + m * D_DIM;
#pragma unroll
        for (int ni = 0; ni < 4; ni++)
          orow[nidx[ni]] = f2b(p * (acc[mi][ni][j] + bia[ni]));
      } else if (EPI == 3) {
        float p = probs[m * 4 + eIdx];
        u16* orow = outB + m * D_DIM;
#pragma unroll
        for (int ni = 0; ni < 4; ni++)
          orow[nidx[ni]] = f2b(b2f(orow[nidx[ni]]) + p * (acc[mi][ni][j] + bia[ni]));
      } else {
        float p = probs[m * 4 + eIdx];
        const u16* srow = outB + m * D_DIM;
        float* orow = outF + m * D_DIM;
#pragma unroll
        for (int ni = 0; ni < 4; ni++)
          orow[nidx[ni]] = b2f(srow[nidx[ni]]) + p * (acc[mi][ni][j] + bia[ni]);
      }
    }
}

// Row LayerNorm over D=1024 on bf16 input; writes bf16 (next A) and optionally f32.
template <int WF32>
__global__ __launch_bounds__(256) void ln_kernel(const u16* __restrict__ src,
                                                 const float* __restrict__ gamma,
                                                 const float* __restrict__ beta,
                                                 float* __restrict__ dstF, u16* __restrict__ dstB) {
  size_t row = blockIdx.x;
  int t = threadIdx.x, w = t >> 6, l = t & 63;
  u16x4 vb = ((const u16x4*)(src + row * D_DIM))[t];
  float v[4];
#pragma unroll
  for (int i = 0; i < 4; i++) v[i] = b2f(vb[i]);
  float s = v[0] + v[1] + v[2] + v[3];
  float q = v[0]*v[0] + v[1]*v[1] + v[2]*v[2] + v[3]*v[3];
#pragma unroll
  for (int off = 32; off; off >>= 1) { s += __shfl_xor(s, off); q += __shfl_xor(q, off); }
  __shared__ float red[8];
  if (l == 0) { red[w] = s; red[4 + w] = q; }
  __syncthreads();
  s = red[0] + red[1] + red[2] + red[3];
  q = red[4] + red[5] + red[6] + red[7];
  float mu = s * (1.0f / 1024.0f);
  float var = q * (1.0f / 1024.0f) - mu * mu;
  float inv = rsqrtf(var + 1e-5f);
  f32x4 gm = ((const f32x4*)gamma)[t], b = ((const f32x4*)beta)[t];
  f32x4 y; u16x4 yb;
#pragma unroll
  for (int i = 0; i < 4; i++) { y[i] = (v[i] - mu) * inv * gm[i] + b[i]; yb[i] = f2b(y[i]); }
  ((u16x4*)(dstB + row * D_DIM))[t] = yb;
  if (WF32) ((f32x4*)(dstF + row * D_DIM))[t] = y;
}

// f32 -> bf16 elementwise
__global__ void conv_kernel(const float* __restrict__ src, u16* __restrict__ dst, int n4) {
  int i = blockIdx.x * 256 + threadIdx.x;
  if (i >= n4) return;
  f32x4 v = ((const f32x4*)src)[i];
  u16x4 o;
#pragma unroll
  for (int j = 0; j < 4; j++) o[j] = f2b(v[j]);
  ((u16x4*)dst)[i] = o;
}

// Gate: logits + softmax -> probs[m,0..3]. One wave per row.
__global__ __launch_bounds__(256) void gate_kernel(const u16* __restrict__ zb,
                                                   const float* __restrict__ gW,
                                                   const float* __restrict__ gb,
                                                   float* __restrict__ probs) {
  __shared__ float sW[4096];
  int t = threadIdx.x;
#pragma unroll
  for (int c = 0; c < 4; c++) ((f32x4*)sW)[c * 256 + t] = ((const f32x4*)gW)[c * 256 + t];
  __syncthreads();
  int w = t >> 6, l = t & 63;
  size_t m = (size_t)blockIdx.x * 4 + w;
  const u16* zr = zb + m * D_DIM;
  float d0 = 0, d1 = 0, d2 = 0, d3 = 0;
#pragma unroll
  for (int c = 0; c < 4; c++) {
    int k = l * 4 + c * 256;
    u16x4 zv = *(const u16x4*)(zr + k);
    f32x4 w0 = *(const f32x4*)&sW[k];
    f32x4 w1 = *(const f32x4*)&sW[1024 + k];
    f32x4 w2 = *(const f32x4*)&sW[2048 + k];
    f32x4 w3 = *(const f32x4*)&sW[3072 + k];
#pragma unroll
    for (int i = 0; i < 4; i++) {
      float zf = b2f(zv[i]);
      d0 += zf * w0[i]; d1 += zf * w1[i]; d2 += zf * w2[i]; d3 += zf * w3[i];
    }
  }
#pragma unroll
  for (int off = 32; off; off >>= 1) {
    d0 += __shfl_xor(d0, off); d1 += __shfl_xor(d1, off);
    d2 += __shfl_xor(d2, off); d3 += __shfl_xor(d3, off);
  }
  if (l == 0) {
    float l0 = d0 + gb[0], l1 = d1 + gb[1], l2 = d2 + gb[2], l3 = d3 + gb[3];
    float mx = fmaxf(fmaxf(l0, l1), fmaxf(l2, l3));
    float e0 = __expf(l0 - mx), e1 = __expf(l1 - mx), e2 = __expf(l2 - mx), e3 = __expf(l3 - mx);
    float inv = 1.0f / (e0 + e1 + e2 + e3);
    f32x4 r; r[0] = e0 * inv; r[1] = e1 * inv; r[2] = e2 * inv; r[3] = e3 * inv;
    ((f32x4*)(probs + m * 4))[0] = r;
  }
}

extern "C" void kernel_launch(void* const* d_in, const int* in_sizes, int n_in,
                              void* d_out, int out_size, void* d_ws, size_t ws_size,
                              hipStream_t stream) {
  (void)in_sizes; (void)n_in; (void)out_size; (void)ws_size;
  const float* x_ctx    = (const float*)d_in[0];
  const float* x_tgt    = (const float*)d_in[1];
  const float* enc_Win  = (const float*)d_in[2];
  const float* enc_bin  = (const float*)d_in[3];
  const float* enc_dec  = (const float*)d_in[4];
  const float* enc_Wout = (const float*)d_in[5];
  const float* enc_bout = (const float*)d_in[6];
  const float* enc_gam  = (const float*)d_in[7];
  const float* enc_bet  = (const float*)d_in[8];
  const float* tgt_Win  = (const float*)d_in[9];
  const float* tgt_bin  = (const float*)d_in[10];
  const float* tgt_dec  = (const float*)d_in[11];
  const float* tgt_Wout = (const float*)d_in[12];
  const float* tgt_bout = (const float*)d_in[13];
  const float* tgt_gam  = (const float*)d_in[14];
  const float* tgt_bet  = (const float*)d_in[15];
  const float* gate_W   = (const float*)d_in[16];
  const float* gate_b   = (const float*)d_in[17];
  const float* exp_W    = (const float*)d_in[18];
  const float* exp_b    = (const float*)d_in[19];

  // d_out: pred_z[16M] | gate_probs[64K] | z_target[16M]
  float* out_pred  = (float*)d_out;
  float* out_probs = out_pred + (size_t)M_TOT * D_DIM;
  float* out_ztgt  = out_probs + (size_t)M_TOT * 4;

  // ws: bf16 weights (32MB) | xb(32MB) | sb(32MB) | ob(32MB)
  char* ws = (char*)d_ws;
  u16* wbEncIn  = (u16*)ws;
  u16* wbEncOut = wbEncIn  + (size_t)3 * 1048576;
  u16* wbTgtIn  = wbEncOut + (size_t)3 * 1048576;
  u16* wbTgtOut = wbTgtIn  + (size_t)3 * 1048576;
  u16* wbExp    = wbTgtOut + (size_t)3 * 1048576;
  u16* xb       = wbExp    + (size_t)4 * 1048576;
  u16* sb       = xb + (size_t)M_TOT * D_DIM;
  u16* ob       = sb + (size_t)M_TOT * D_DIM;

  auto conv = [&](const float* s, u16* d, size_t n) {
    int n4 = (int)(n / 4);
    conv_kernel<<<(n4 + 255) / 256, 256, 0, stream>>>(s, d, n4);
  };
  conv(enc_Win,  wbEncIn,  (size_t)3 * 1048576);
  conv(enc_Wout, wbEncOut, (size_t)3 * 1048576);
  conv(tgt_Win,  wbTgtIn,  (size_t)3 * 1048576);
  conv(tgt_Wout, wbTgtOut, (size_t)3 * 1048576);
  conv(exp_W,    wbExp,    (size_t)4 * 1048576);

  // ---- target stack ----
  conv(x_tgt, xb, (size_t)M_TOT * D_DIM);
  for (int i = 0; i < N_LAYERS; i++) {
    gemm8p<0><<<256, 512, 0, stream>>>(xb, wbTgtIn + (size_t)i * 1048576,
                                       tgt_bin + i * 1024, tgt_dec + i * 1024, xb,
                                       nullptr, 0, sb, nullptr);
    gemm8p<1><<<256, 512, 0, stream>>>(sb, wbTgtOut + (size_t)i * 1048576,
                                       tgt_bout + i * 1024, nullptr, xb,
                                       nullptr, 0, ob, nullptr);
    if (i == N_LAYERS - 1)
      ln_kernel<1><<<M_TOT, 256, 0, stream>>>(ob, tgt_gam + i * 1024, tgt_bet + i * 1024, out_ztgt, xb);
    else
      ln_kernel<0><<<M_TOT, 256, 0, stream>>>(ob, tgt_gam + i * 1024, tgt_bet + i * 1024, nullptr, xb);
  }

  // ---- context stack ----
  conv(x_ctx, xb, (size_t)M_TOT * D_DIM);
  for (int i = 0; i < N_LAYERS; i++) {
    gemm8p<0><<<256, 512, 0, stream>>>(xb, wbEncIn + (size_t)i * 1048576,
                                       enc_bin + i * 1024, enc_dec + i * 1024, xb,
                                       nullptr, 0, sb, nullptr);
    gemm8p<1><<<256, 512, 0, stream>>>(sb, wbEncOut + (size_t)i * 1048576,
                                       enc_bout + i * 1024, nullptr, xb,
                                       nullptr, 0, ob, nullptr);
    ln_kernel<0><<<M_TOT, 256, 0, stream>>>(ob, enc_gam + i * 1024, enc_bet + i * 1024, nullptr, xb);
  }

  // ---- MoE head: gate probs, then 4 passes; bf16 running sum in sb ----
  gate_kernel<<<M_TOT / 4, 256, 0, stream>>>(xb, gate_W, gate_b, out_probs);
  gemm8p<2><<<256, 512, 0, stream>>>(xb, wbExp,               exp_b,        nullptr, nullptr,
                                     out_probs, 0, sb, nullptr);
  gemm8p<3><<<256, 512, 0, stream>>>(xb, wbExp + 1048576,     exp_b + 1024, nullptr, nullptr,
                                     out_probs, 1, sb, nullptr);
  gemm8p<3><<<256, 512, 0, stream>>>(xb, wbExp + 2 * 1048576, exp_b + 2048, nullptr, nullptr,
                                     out_probs, 2, sb, nullptr);
  gemm8p<4><<<256, 512, 0, stream>>>(xb, wbExp + 3 * 1048576, exp_b + 3072, nullptr, nullptr,
                                     out_probs, 3, sb, out_pred);
}